// Round 5
// baseline (432.151 us; speedup 1.0000x reference)
//
#include <hip/hip_runtime.h>
#include <hip/hip_bf16.h>
#include <cstddef>
#include <cstdint>

#define NB 128
#define NT 4096
#define NC 32
#define BITROWS 5457
#define S01_ROWS 17                      // qv rows (scales 0..1) in ws
#define QOUT_ELEMS (NB*NT*NC)            // 16777216
#define BITS_ELEMS (NB*BITROWS*NC)       // 22351872

// ws layout: qv (128*17*32 f32 = 278,528 B) | acc (204 f64 @ 278528) | S16 (4 MB @ 280160)
#define ACC_OFF  278528
#define S16_OFF  280160

__device__ __constant__ float kQSC = 0.17677669529663687f;   // 1/sqrt(32)
__device__ __constant__ float kSIG = 17.67766952966369f;     // 100/sqrt(32)

// ---- R4-exact interp: x[lo]*(1-w) + x[hi]*w, explicit rn ops (no contraction) ----
__device__ __forceinline__ float interp_evalS(const float* __restrict__ qbase, int sb, int P,
                                              float scale, int t, int c) {
  float pos = ((float)t + 0.5f) * scale - 0.5f;
  pos = fminf(fmaxf(pos, 0.0f), (float)(P - 1));
  const int lo = (int)pos;
  const int hi = min(lo + 1, P - 1);
  const float w = pos - (float)lo;
  const float a = __fmul_rn(qbase[(lo - sb) * NC + c], 1.0f - w);
  const float b = __fmul_rn(qbase[(hi - sb) * NC + c], w);
  return __fadd_rn(a, b);
}

// ---- R4-exact quantize core: butterfly shfl_xor(16..1), IEEE sqrt/div, fn+(zh-fn) ----
__device__ __forceinline__ void quant_core(float m, float& qvv, float& fn, bool& bit) {
  float ss = m * m;
  #pragma unroll
  for (int mk = 16; mk; mk >>= 1) ss += __shfl_xor(ss, mk, 32);
  const float den = fmaxf(sqrtf(ss), 1e-12f);
  fn = m / den;
  bit = fn > 0.0f;
  const float zh = bit ? kQSC : -kQSC;
  qvv = fn + (zh - fn);                  // R4-exact (f32 != zh in general)
}

// loss pieces (loss-only path; tolerance ~2e-2)
__device__ __forceinline__ void loss_piece(float fn, float qvv, float& p, float& ent, float& c2) {
  const float arg = (-4.0f * fn) * kSIG;
  p = __builtin_amdgcn_rcpf(1.0f + __expf(-arg));
  ent = -(p * __logf(p + 1e-8f) + (1.0f - p) * __logf((1.0f - p) + 1e-8f));
  const float d = qvv - fn;
  c2 = d * d;
}

// block loss reduction -> f64 atomics; all threads must call
__device__ __forceinline__ void reduce_losses(
    int sIdx, float entA, float comA, float pA, int tid, int nWaves,
    double* __restrict__ acc, float* redE, float* redC, float* redP)
{
  float e = entA, cm = comA;
  #pragma unroll
  for (int mk = 32; mk; mk >>= 1) { e += __shfl_xor(e, mk, 64); cm += __shfl_xor(cm, mk, 64); }
  const float p = pA + __shfl_xor(pA, 32, 64);
  const int w = tid >> 6, lane = tid & 63;
  if (lane == 0) { redE[w] = e; redC[w] = cm; }
  if (lane < 32) redP[w * 32 + lane] = p;
  __syncthreads();
  if (tid == 0) {
    double te = 0.0, tc = 0.0;
    for (int i = 0; i < nWaves; ++i) { te += (double)redE[i]; tc += (double)redC[i]; }
    atomicAdd(&acc[sIdx], te);
    atomicAdd(&acc[6 + sIdx], tc);
  }
  if (tid < 32) {
    float tp = 0.0f;
    for (int i = 0; i < nWaves; ++i) tp += redP[i * 32 + tid];
    atomicAdd(&acc[12 + sIdx * 32 + tid], (double)tp);
  }
  __syncthreads();
}

// ---------- P0: granularity-16 channel sums of f, float4 ----------
__global__ __launch_bounds__(256) void k_sum16(const float4* __restrict__ f4, float4* __restrict__ S4) {
  const int idx = blockIdx.x * 256 + threadIdx.x;       // NB*256*8 = 262144
  const int c4 = idx & 7;
  const int j  = (idx >> 3) & 255;
  const int b  = idx >> 11;
  const float4* p = f4 + (size_t)b * 32768 + (size_t)j * 128 + c4;
  float4 s = {0.f, 0.f, 0.f, 0.f};
  #pragma unroll
  for (int k = 0; k < 16; ++k) {
    const float4 v = p[k * 8];
    s.x += v.x; s.y += v.y; s.z += v.z; s.w += v.w;
  }
  S4[idx] = s;
}

// ---------- P1: scales 0..1 per batch (R4-exact chain) ----------
__global__ __launch_bounds__(1024) void k_s01(
    const float* __restrict__ S16g, float* __restrict__ qv,
    float* __restrict__ bitsOut, double* __restrict__ acc)
{
  __shared__ float red[1024];
  __shared__ float q0s[NC];
  __shared__ float redE[16], redC[16], redP[16 * 32];
  const int b = blockIdx.x, tid = threadIdx.x;
  const int c = tid & 31, g = tid >> 5;
  const size_t sb = (size_t)b * 8192;
  const size_t qb = (size_t)b * (S01_ROWS * NC);
  const size_t bb = (size_t)b * (BITROWS * NC);

  // scale 0 (pt=1): R4-exact reduction tree
  float entA = 0.f, comA = 0.f, pA = 0.f;
  {
    float part = 0.0f;
    #pragma unroll
    for (int j = 0; j < 8; ++j) part += S16g[sb + (size_t)(g * 8 + j) * NC + c];
    red[tid] = part;
  }
  __syncthreads();
  if (tid < 32) {
    float msum = 0.0f;
    for (int g2 = 0; g2 < 32; ++g2) msum += red[g2 * 32 + tid];
    float qvv, fn; bool bit;
    quant_core(msum * (1.0f / 4096.0f), qvv, fn, bit);
    q0s[tid] = qvv;
    qv[qb + tid] = qvv;
    bitsOut[bb + tid] = bit ? 1.0f : 0.0f;
    float p, ent, c2; loss_piece(fn, qvv, p, ent, c2);
    entA = ent; comA = c2; pA = p;
  }
  reduce_losses(0, entA, comA, pA, tid, 16, acc, redE, redC, redP);  // fences q0s

  // scale 1 (pt=16): msum over 16 rows of (S16 - corr), same op order as R4
  entA = comA = pA = 0.f;
  const float corr = 16.0f * q0s[c];
  if (tid < 512) {
    const int j = tid >> 5;
    float msum = 0.0f;
    for (int jj = 0; jj < 16; ++jj)
      msum += (S16g[sb + (size_t)(j * 16 + jj) * NC + c] - corr);
    float qvv, fn; bool bit;
    quant_core(msum * (1.0f / 256.0f), qvv, fn, bit);
    qv[qb + (size_t)(1 + j) * NC + c] = qvv;
    bitsOut[bb + (size_t)(1 + j) * NC + c] = bit ? 1.0f : 0.0f;
    float p, ent, c2; loss_piece(fn, qvv, p, ent, c2);
    entA = ent; comA = c2; pA = p;
  }
  reduce_losses(1, entA, comA, pA, tid, 16, acc, redE, redC, redP);
}

// ---------- P2: fused scales 2..5 per (b, 128-t tile) — R4-exact chains ----------
__global__ __launch_bounds__(256, 8) void k_fused(
    const float* __restrict__ f, const float* __restrict__ S16g,
    const float* __restrict__ qv, float* __restrict__ qout,
    float* __restrict__ bitsOut, double* __restrict__ acc)
{
  __shared__ float qsl[S01_ROWS * NC];  // q0 (1 row) + q1 (16 rows)
  __shared__ float Sres[16 * NC];       // S16-residual rows [R16B, R16B+15]
  __shared__ float q2l[4 * NC];         // local q2 slice, base S2B
  __shared__ float q3l[12 * NC];        // local q3 slice, base S3B
  __shared__ float rp[136 * NC];        // per-t residual after scales 0..3
  __shared__ float q4r[34 * NC];        // scale-4 q rows incl boundaries, base R0
  __shared__ float redE[4], redC[4], redP[4 * 32];

  const int b = blockIdx.x >> 5, seg = blockIdx.x & 31;
  const int t0 = seg << 7;
  const int tid = threadIdx.x, c = tid & 31, rloc = tid >> 5;
  const int R0 = max(t0 / 4 - 1, 0);
  const int R1v = min(t0 / 4 + 32, 1023);
  const int tb = R0 * 4, tn = (R1v - R0 + 1) * 4;
  const int S2B = min(max(t0 / 64 - 1, 0), 60);    // q2 slice base (4 rows) — R4-verified
  const int S3B = min(max(tb / 16 - 1, 0), 244);   // q3 slice base (12 rows)
  const int R16B = 4 * S2B;                        // S16 rows [R16B, R16B+15]
  const size_t fb = (size_t)b * (NT * NC);
  const size_t bbits = (size_t)b * (BITROWS * NC);

  for (int e = tid; e < S01_ROWS * NC; e += 256)
    qsl[e] = qv[(size_t)b * (S01_ROWS * NC) + e];
  __syncthreads();

  // phase 0a: Sres = (S16 - corr) - cs1   (R4 k_coarse chain, halo recompute)
  const float corr = 16.0f * qsl[c];
  for (int e = tid; e < 16 * NC; e += 256) {
    const int i = e >> 5;
    const int r16 = R16B + i;
    const float raw = S16g[(size_t)b * 8192 + (size_t)r16 * NC + c];
    float cs = 0.0f;
    #pragma unroll
    for (int k = 0; k < 16; ++k)
      cs += interp_evalS(qsl + NC, 0, 16, 0.00390625f, r16 * 16 + k, c);
    Sres[e] = (raw - corr) - cs;
  }
  __syncthreads();

  // phase 0b: quantize q2 slice (4 rows); bits/losses only for owned 2 rows
  float entA = 0.f, comA = 0.f, pA = 0.f;
  if (tid < 128) {
    const int jj = tid >> 5;
    const int j = S2B + jj;
    const int base = (4 * jj) * NC + c;
    const float msum = Sres[base] + Sres[base + NC] + Sres[base + 2 * NC] + Sres[base + 3 * NC];
    float qvv, fn; bool bit;
    quant_core(msum * (1.0f / 64.0f), qvv, fn, bit);
    q2l[jj * NC + c] = qvv;
    if (j >= (t0 >> 6) && j < (t0 >> 6) + 2) {
      bitsOut[bbits + (size_t)(17 + j) * NC + c] = bit ? 1.0f : 0.0f;
      float p, ent, c2; loss_piece(fn, qvv, p, ent, c2);
      entA += ent; comA += c2; pA += p;
    }
  }
  reduce_losses(2, entA, comA, pA, tid, 4, acc, redE, redC, redP);   // fences q2l + Sres reads

  // phase 0c: Sres -= cs2, quantize q3 slice (12 rows); owned = 8 rows
  entA = comA = pA = 0.f;
  for (int e = tid; e < 12 * NC; e += 256) {
    const int i2 = e >> 5;
    const int j3 = S3B + i2;
    const int iloc = j3 - R16B;
    float cs = 0.0f;
    #pragma unroll
    for (int k = 0; k < 16; ++k)
      cs += interp_evalS(q2l, S2B, 64, 0.015625f, j3 * 16 + k, c);
    const float v = Sres[iloc * NC + c] - cs;
    float qvv, fn; bool bit;
    quant_core(v * 0.0625f, qvv, fn, bit);
    q3l[i2 * NC + c] = qvv;
    if (j3 >= (t0 >> 4) && j3 < (t0 >> 4) + 8) {
      bitsOut[bbits + (size_t)(81 + j3) * NC + c] = bit ? 1.0f : 0.0f;
      float p, ent, c2; loss_piece(fn, qvv, p, ent, c2);
      entA += ent; comA += c2; pA += p;
    }
  }
  reduce_losses(3, entA, comA, pA, tid, 4, acc, redE, redC, redP);   // fences q3l

  // phase 1: per-t residual after scales 0..3 (R4-exact chain order)
  for (int pass = 0; pass < 17; ++pass) {
    const int tt = tb + pass * 8 + rloc;
    if (tt < tb + tn) {
      const float fv = f[fb + (size_t)tt * NC + c];
      float r = fv - qsl[c];
      r -= interp_evalS(qsl + NC, 0,   16,  0.00390625f, tt, c);
      r -= interp_evalS(q2l,      S2B, 64,  0.015625f,   tt, c);
      r -= interp_evalS(q3l,      S3B, 256, 0.0625f,     tt, c);
      rp[(tt - tb) * NC + c] = r;
    }
  }
  __syncthreads();

  // phase 2: scale-4 rows (boundary rows recomputed; bits/losses only for owned)
  entA = comA = pA = 0.f;
  for (int pass = 0; pass < 5; ++pass) {
    const int j = R0 + pass * 8 + rloc;
    if (j <= R1v) {
      const int base = (4 * j - tb) * NC + c;
      const float msum = rp[base] + rp[base + NC] + rp[base + 2 * NC] + rp[base + 3 * NC];
      float qvv, fn; bool bit;
      quant_core(msum * 0.25f, qvv, fn, bit);
      q4r[(j - R0) * NC + c] = qvv;
      if (j >= t0 / 4 && j < t0 / 4 + 32) {
        bitsOut[bbits + (size_t)(337 + j) * NC + c] = bit ? 1.0f : 0.0f;
        float p, ent, c2; loss_piece(fn, qvv, p, ent, c2);
        entA += ent; comA += c2; pA += p;
      }
    }
  }
  reduce_losses(4, entA, comA, pA, tid, 4, acc, redE, redC, redP);   // fences q4r

  // phase 3: scale 5 (pt=T) + outputs (f re-read, L2-hot; qpre = fv - rp identical FP)
  entA = comA = pA = 0.f;
  for (int pass = 0; pass < 16; ++pass) {
    const int t = t0 + pass * 8 + rloc;
    const float fv = f[fb + (size_t)t * NC + c];
    const float rpv = rp[(t - tb) * NC + c];
    const float q4 = interp_evalS(q4r, R0, 1024, 0.25f, t, c);
    const float r = rpv - q4;
    float qvv, fn; bool bit;
    quant_core(r, qvv, fn, bit);
    const float qpre = fv - rpv;
    qout[fb + (size_t)t * NC + c] = (qpre + q4) + qvv;
    bitsOut[bbits + (size_t)(1361 + t) * NC + c] = bit ? 1.0f : 0.0f;
    float p, ent, c2; loss_piece(fn, qvv, p, ent, c2);
    entA += ent; comA += c2; pA += p;
  }
  reduce_losses(5, entA, comA, pA, tid, 4, acc, redE, redC, redP);
}

// ---------- P3: finalize 6 scalar losses ----------
__global__ void k_losses(const double* __restrict__ acc, float* __restrict__ out) {
  const int s = threadIdx.x;
  if (s >= 6) return;
  const int pts[6] = {1, 16, 64, 256, 1024, 4096};
  const double n = 128.0 * (double)pts[s];
  const double pse = acc[s] / n;
  const double commit = acc[6 + s] / n;
  double cbe = 0.0;
  for (int c = 0; c < 32; ++c) {
    const double ap = acc[12 + s * 32 + c] / n;
    cbe += -(ap * log(ap + 1e-8) + (1.0 - ap) * log((1.0 - ap) + 1e-8));
  }
  const double pen = (pse - cbe) / 100.0;
  out[s] = (float)(pen * 0.1 + commit * 0.2);
}

extern "C" void kernel_launch(void* const* d_in, const int* in_sizes, int n_in,
                              void* d_out, int out_size, void* d_ws, size_t ws_size,
                              hipStream_t stream) {
  const float* f = (const float*)d_in[0];
  float* qout = (float*)d_out;
  float* bitsOut = qout + QOUT_ELEMS;
  float* lossesOut = qout + (QOUT_ELEMS + BITS_ELEMS);
  float* qv = (float*)d_ws;
  double* acc = (double*)((char*)d_ws + ACC_OFF);
  float* S16 = (float*)((char*)d_ws + S16_OFF);

  hipMemsetAsync(acc, 0, 204 * sizeof(double), stream);
  k_sum16<<<1024, 256, 0, stream>>>((const float4*)f, (float4*)S16);
  k_s01<<<NB, 1024, 0, stream>>>(S16, qv, bitsOut, acc);
  k_fused<<<NB * 32, 256, 0, stream>>>(f, S16, qv, qout, bitsOut, acc);
  k_losses<<<1, 64, 0, stream>>>(acc, lossesOut);
}

// Round 6
// 379.494 us; speedup vs baseline: 1.1388x; 1.1388x over previous
//
#include <hip/hip_runtime.h>
#include <hip/hip_bf16.h>
#include <cstddef>
#include <cstdint>

#define NB 128
#define NT 4096
#define NC 32
#define BITROWS 5457
#define CQ_ROWS 337                      // coarse q rows (scales 0..3) in ws
#define QOUT_ELEMS (NB*NT*NC)            // 16777216
#define BITS_ELEMS (NB*BITROWS*NC)       // 22351872

// ws layout: qv (128*337*32 f32 = 5,521,408 B) | acc (204 f64) | S16 (4 MB)
#define ACC_OFF  5521408
#define S16_OFF  5523456

__device__ __constant__ float kQSC = 0.17677669529663687f;   // 1/sqrt(32)
__device__ __constant__ float kSIG = 17.67766952966369f;     // 100/sqrt(32)

// ---- R4-exact interp: x[lo]*(1-w) + x[hi]*w, explicit rn ops (no contraction) ----
__device__ __forceinline__ float interp_eval(const float* __restrict__ q, int P, int t, int c) {
  float pos = ((float)t + 0.5f) * ((float)P * (1.0f / 4096.0f)) - 0.5f;
  pos = fminf(fmaxf(pos, 0.0f), (float)(P - 1));
  const int lo = (int)pos;
  const int hi = min(lo + 1, P - 1);
  const float w = pos - (float)lo;
  const float a = __fmul_rn(q[lo * NC + c], 1.0f - w);
  const float b = __fmul_rn(q[hi * NC + c], w);
  return __fadd_rn(a, b);
}

// sliced variant (identical FP sequence; only integer indexing differs)
__device__ __forceinline__ float interp_evalS(const float* __restrict__ qbase, int sb, int P,
                                              float scale, int t, int c) {
  float pos = ((float)t + 0.5f) * scale - 0.5f;
  pos = fminf(fmaxf(pos, 0.0f), (float)(P - 1));
  const int lo = (int)pos;
  const int hi = min(lo + 1, P - 1);
  const float w = pos - (float)lo;
  const float a = __fmul_rn(qbase[(lo - sb) * NC + c], 1.0f - w);
  const float b = __fmul_rn(qbase[(hi - sb) * NC + c], w);
  return __fadd_rn(a, b);
}

// ---- R4-exact quantize core: butterfly shfl_xor(16..1), IEEE sqrt/div, fn+(zh-fn) ----
__device__ __forceinline__ void quant_core(float m, float& qvv, float& fn, bool& bit) {
  float ss = m * m;
  #pragma unroll
  for (int mk = 16; mk; mk >>= 1) ss += __shfl_xor(ss, mk, 32);
  const float den = fmaxf(sqrtf(ss), 1e-12f);
  fn = m / den;
  bit = fn > 0.0f;
  const float zh = bit ? kQSC : -kQSC;
  qvv = fn + (zh - fn);                  // R4-exact (f32 != zh in general)
}

// loss pieces (loss-only path; tolerance ~2e-2)
__device__ __forceinline__ void loss_piece(float fn, float qvv, float& p, float& ent, float& c2) {
  const float arg = (-4.0f * fn) * kSIG;
  p = __builtin_amdgcn_rcpf(1.0f + __expf(-arg));
  ent = -(p * __logf(p + 1e-8f) + (1.0f - p) * __logf((1.0f - p) + 1e-8f));
  const float d = qvv - fn;
  c2 = d * d;
}

// R4-exact per-coarse-element (writes qv + bits, accumulates losses)
__device__ __forceinline__ void process_elem(
    float msum, float invn, int b, int rowOff, int j, int c,
    float* qlsRow, float* __restrict__ qvG, float* __restrict__ bitsG,
    float& entA, float& comA, float& pA)
{
  const float m = msum * invn;           // invn power of two -> exact
  float qvv, fn; bool bit;
  quant_core(m, qvv, fn, bit);
  if (qlsRow) qlsRow[c] = qvv;
  qvG[(size_t)b * (CQ_ROWS * NC) + (size_t)(rowOff + j) * NC + c] = qvv;
  bitsG[(size_t)b * (BITROWS * NC) + (size_t)(rowOff + j) * NC + c] = bit ? 1.0f : 0.0f;
  float p, ent, c2;
  loss_piece(fn, qvv, p, ent, c2);
  entA += ent; comA += c2; pA += p;
}

// block loss reduction -> f64 atomics; all threads must call
__device__ __forceinline__ void reduce_losses(
    int sIdx, float entA, float comA, float pA, int tid, int nWaves,
    double* __restrict__ acc, float* redE, float* redC, float* redP)
{
  float e = entA, cm = comA;
  #pragma unroll
  for (int mk = 32; mk; mk >>= 1) { e += __shfl_xor(e, mk, 64); cm += __shfl_xor(cm, mk, 64); }
  const float p = pA + __shfl_xor(pA, 32, 64);
  const int w = tid >> 6, lane = tid & 63;
  if (lane == 0) { redE[w] = e; redC[w] = cm; }
  if (lane < 32) redP[w * 32 + lane] = p;
  __syncthreads();
  if (tid == 0) {
    double te = 0.0, tc = 0.0;
    for (int i = 0; i < nWaves; ++i) { te += (double)redE[i]; tc += (double)redC[i]; }
    atomicAdd(&acc[sIdx], te);
    atomicAdd(&acc[6 + sIdx], tc);
  }
  if (tid < 32) {
    float tp = 0.0f;
    for (int i = 0; i < nWaves; ++i) tp += redP[i * 32 + tid];
    atomicAdd(&acc[12 + sIdx * 32 + tid], (double)tp);
  }
  __syncthreads();
}

// ---------- P0: granularity-16 channel sums of f, float4 ----------
__global__ __launch_bounds__(256) void k_sum16(const float4* __restrict__ f4, float4* __restrict__ S4) {
  const int idx = blockIdx.x * 256 + threadIdx.x;       // NB*256*8 = 262144
  const int c4 = idx & 7;
  const int j  = (idx >> 3) & 255;
  const int b  = idx >> 11;
  const float4* p = f4 + (size_t)b * 32768 + (size_t)j * 128 + c4;
  float4 s = {0.f, 0.f, 0.f, 0.f};
  #pragma unroll
  for (int k = 0; k < 16; ++k) {
    const float4 v = p[k * 8];
    s.x += v.x; s.y += v.y; s.z += v.z; s.w += v.w;
  }
  S4[idx] = s;
}

// ---------- P1: scales 0..3 per batch, LDS-resident — R4 VERBATIM ----------
__global__ __launch_bounds__(1024) void k_coarse(
    const float* __restrict__ S16g, float* __restrict__ qv,
    float* __restrict__ bitsOut, double* __restrict__ acc)
{
  __shared__ float S[256 * NC];          // 32 KB granularity-16 residual sums
  __shared__ float qls[81 * NC];
  __shared__ float red[1024];
  __shared__ float redE[16], redC[16], redP[16 * 32];
  const int b = blockIdx.x, tid = threadIdx.x;
  const int c = tid & 31;

  for (int e = tid; e < 256 * NC; e += 1024) S[e] = S16g[(size_t)b * 8192 + e];
  __syncthreads();

  float entA, comA, pA;

  // ----- scale 0 (pt=1) -----
  entA = comA = pA = 0.0f;
  {
    const int g = tid >> 5;
    float part = 0.0f;
    #pragma unroll
    for (int j = 0; j < 8; ++j) part += S[(g * 8 + j) * NC + c];
    red[tid] = part;
  }
  __syncthreads();
  if (tid < 32) {
    float msum = 0.0f;
    for (int g = 0; g < 32; ++g) msum += red[g * 32 + tid];
    process_elem(msum, 1.0f / 4096.0f, b, 0, 0, tid, &qls[0], qv, bitsOut, entA, comA, pA);
  }
  reduce_losses(0, entA, comA, pA, tid, 16, acc, redE, redC, redP);
  {
    const float corr = 16.0f * qls[c];
    for (int e = tid; e < 8192; e += 1024) S[e] -= corr;
  }
  __syncthreads();

  // ----- scale 1 (pt=16) -----
  entA = comA = pA = 0.0f;
  if (tid < 512) {
    const int j = tid >> 5;
    float msum = 0.0f;
    for (int jj = 0; jj < 16; ++jj) msum += S[(j * 16 + jj) * NC + c];
    process_elem(msum, 1.0f / 256.0f, b, 1, j, c, &qls[(1 + j) * NC], qv, bitsOut, entA, comA, pA);
  }
  reduce_losses(1, entA, comA, pA, tid, 16, acc, redE, redC, redP);
  for (int e = tid; e < 8192; e += 1024) {
    const int jj = e >> 5;
    float cs = 0.0f;
    #pragma unroll
    for (int k = 0; k < 16; ++k) cs += interp_eval(&qls[1 * NC], 16, jj * 16 + k, c);
    S[e] -= cs;
  }
  __syncthreads();

  // ----- scale 2 (pt=64) -----
  entA = comA = pA = 0.0f;
  for (int out = tid; out < 2048; out += 1024) {
    const int j = out >> 5;
    float msum = 0.0f;
    #pragma unroll
    for (int jj = 0; jj < 4; ++jj) msum += S[(j * 4 + jj) * NC + c];
    process_elem(msum, 1.0f / 64.0f, b, 17, j, c, &qls[(17 + j) * NC], qv, bitsOut, entA, comA, pA);
  }
  reduce_losses(2, entA, comA, pA, tid, 16, acc, redE, redC, redP);
  for (int e = tid; e < 8192; e += 1024) {
    const int jj = e >> 5;
    float cs = 0.0f;
    #pragma unroll
    for (int k = 0; k < 16; ++k) cs += interp_eval(&qls[17 * NC], 64, jj * 16 + k, c);
    S[e] -= cs;
  }
  __syncthreads();

  // ----- scale 3 (pt=256) -----
  entA = comA = pA = 0.0f;
  for (int out = tid; out < 8192; out += 1024) {
    const int j = out >> 5;
    process_elem(S[out], 1.0f / 16.0f, b, 81, j, c, nullptr, qv, bitsOut, entA, comA, pA);
  }
  reduce_losses(3, entA, comA, pA, tid, 16, acc, redE, redC, redP);
}

// ---------- P2: fused scales 4+5 per (b, 128-t tile) — R4 numerics, slim LDS ----------
__global__ __launch_bounds__(256, 8) void k_fused(
    const float* __restrict__ f, const float* __restrict__ qv,
    float* __restrict__ qout, float* __restrict__ bitsOut, double* __restrict__ acc)
{
  __shared__ float qsl[33 * NC];        // slices: s0(1) s1(16) s2(4) s3(12)
  __shared__ float rp[136 * NC];        // residual after scales 0..3, extended range
  __shared__ float q4r[34 * NC];        // scale-4 q rows incl boundaries
  __shared__ float redE[4], redC[4], redP[4 * 32];
  // qpre dropped (R5-validated FP-equivalent recompute): LDS 43 KB -> ~26.6 KB -> 6 WG/CU

  const int b = blockIdx.x >> 5, seg = blockIdx.x & 31;
  const int t0 = seg << 7;
  const int tid = threadIdx.x, c = tid & 31, rloc = tid >> 5;
  const int R0 = max(t0 / 4 - 1, 0);
  const int R1v = min(t0 / 4 + 32, 1023);
  const int tb = R0 * 4, tn = (R1v - R0 + 1) * 4;
  // Scale-2 slice base: rows touched are lo in [t0/64-1, t0/64+1], hi up to t0/64+2
  const int S2B = min(max(t0 / 64 - 1, 0), 60);
  // Scale-3 rows touched: [8k-1, 8k+8]; base tb/16-1 = 8k-2, 12 rows covers it.
  const int S3B = min(max(tb / 16 - 1, 0), 244);
  const size_t fb = (size_t)b * (NT * NC);
  const size_t bbits = (size_t)b * (BITROWS * NC);

  for (int e = tid; e < 33 * NC; e += 256) {
    const int r = e >> 5, cc = e & 31;
    int grow;
    if (e < 544)        grow = r;                      // s0 + s1 rows 0..16
    else if (e < 672)   grow = 17 + S2B + (r - 17);    // s2 slice (4 rows)
    else                grow = 81 + S3B + (r - 21);    // s3 slice (12 rows)
    qsl[e] = qv[(size_t)b * (CQ_ROWS * NC) + (size_t)grow * NC + cc];
  }
  __syncthreads();

  // phase 1: residual after scales 0..3 (R4-exact chain order)
  for (int pass = 0; pass < 17; ++pass) {
    const int tt = tb + pass * 8 + rloc;
    if (tt < tb + tn) {
      const float fv = f[fb + (size_t)tt * NC + c];
      float r = fv - qsl[c];                                          // == interp(P=1)
      r -= interp_evalS(qsl + 32,  0,   16,  0.00390625f, tt, c);     // scale 1
      r -= interp_evalS(qsl + 544, S2B, 64,  0.015625f,   tt, c);     // scale 2
      r -= interp_evalS(qsl + 672, S3B, 256, 0.0625f,     tt, c);     // scale 3
      rp[(tt - tb) * NC + c] = r;
    }
  }
  __syncthreads();

  // phase 2: scale-4 rows (boundary rows recomputed; bits/losses only for owned)
  float entA = 0.f, comA = 0.f, pA = 0.f;
  for (int pass = 0; pass < 5; ++pass) {
    const int j = R0 + pass * 8 + rloc;
    if (j <= R1v) {
      const int base = (4 * j - tb) * NC + c;
      const float msum = rp[base] + rp[base + NC] + rp[base + 2 * NC] + rp[base + 3 * NC];
      float qvv, fn; bool bit;
      quant_core(msum * 0.25f, qvv, fn, bit);
      q4r[(j - R0) * NC + c] = qvv;
      if (j >= t0 / 4 && j < t0 / 4 + 32) {
        bitsOut[bbits + (size_t)(337 + j) * NC + c] = bit ? 1.0f : 0.0f;
        float p, ent, c2; loss_piece(fn, qvv, p, ent, c2);
        entA += ent; comA += c2; pA += p;
      }
    }
  }
  reduce_losses(4, entA, comA, pA, tid, 4, acc, redE, redC, redP);   // fences q4r

  // phase 3: scale 5 (pt=T) + outputs (f re-read L2-hot; qpre = fv - rpv, R5-validated)
  entA = comA = pA = 0.f;
  for (int pass = 0; pass < 16; ++pass) {
    const int t = t0 + pass * 8 + rloc;
    const float fv = f[fb + (size_t)t * NC + c];
    const float rpv = rp[(t - tb) * NC + c];
    const float q4 = interp_evalS(q4r, R0, 1024, 0.25f, t, c);
    const float r = rpv - q4;                                        // R4-exact final sub
    float qvv, fn; bool bit;
    quant_core(r, qvv, fn, bit);
    const float qpre = fv - rpv;
    qout[fb + (size_t)t * NC + c] = (qpre + q4) + qvv;
    bitsOut[bbits + (size_t)(1361 + t) * NC + c] = bit ? 1.0f : 0.0f;
    float p, ent, c2; loss_piece(fn, qvv, p, ent, c2);
    entA += ent; comA += c2; pA += p;
  }
  reduce_losses(5, entA, comA, pA, tid, 4, acc, redE, redC, redP);
}

// ---------- P3: finalize 6 scalar losses ----------
__global__ void k_losses(const double* __restrict__ acc, float* __restrict__ out) {
  const int s = threadIdx.x;
  if (s >= 6) return;
  const int pts[6] = {1, 16, 64, 256, 1024, 4096};
  const double n = 128.0 * (double)pts[s];
  const double pse = acc[s] / n;
  const double commit = acc[6 + s] / n;
  double cbe = 0.0;
  for (int c = 0; c < 32; ++c) {
    const double ap = acc[12 + s * 32 + c] / n;
    cbe += -(ap * log(ap + 1e-8) + (1.0 - ap) * log((1.0 - ap) + 1e-8));
  }
  const double pen = (pse - cbe) / 100.0;
  out[s] = (float)(pen * 0.1 + commit * 0.2);
}

extern "C" void kernel_launch(void* const* d_in, const int* in_sizes, int n_in,
                              void* d_out, int out_size, void* d_ws, size_t ws_size,
                              hipStream_t stream) {
  const float* f = (const float*)d_in[0];
  float* qout = (float*)d_out;
  float* bitsOut = qout + QOUT_ELEMS;
  float* lossesOut = qout + (QOUT_ELEMS + BITS_ELEMS);
  float* qv = (float*)d_ws;
  double* acc = (double*)((char*)d_ws + ACC_OFF);
  float* S16 = (float*)((char*)d_ws + S16_OFF);

  hipMemsetAsync(acc, 0, 204 * sizeof(double), stream);
  k_sum16<<<1024, 256, 0, stream>>>((const float4*)f, (float4*)S16);
  k_coarse<<<NB, 1024, 0, stream>>>(S16, qv, bitsOut, acc);
  k_fused<<<NB * 32, 256, 0, stream>>>(f, qv, qout, bitsOut, acc);
  k_losses<<<1, 64, 0, stream>>>(acc, lossesOut);
}